// Round 4
// baseline (1118.470 us; speedup 1.0000x reference)
//
#include <hip/hip_runtime.h>
#include <math.h>

// y[b,t,d] = Re(z[t]),  z[t] = r*z[t-1] + x[t],  r = exp(-|decay[d]|)*e^{i freq[d]}
// Single-pass chunked scan with decoupled look-back:
//   - 1024 blocks = 4 batches x 256 chunks of TB=32 timesteps.
//   - Block: local scan (keeps Re(z_loc[t]) in 128 regs), publish aggregate,
//     look-back for incoming state Zin, publish inclusive, write
//     y[t] = yv[t] + Re(r^{t+1} * Zin)  (z[t] = z_loc[t] + r^{t+1} * Zin).
//   - Deadlock-safe under undefined dispatch order via atomic ticket:
//     chunk index = execution-start order, so predecessors are always running.
//   - x read ONCE, y written ONCE: ~256 MiB HBM total.

#define D_DIM  1024
#define TB     32
#define T_DIM  8192
#define CB     (T_DIM / TB)   // 256 chunks per batch
#define B_DIM  4
#define NCHUNK (CB * B_DIM)   // 1024

typedef float floatx4 __attribute__((ext_vector_type(4)));

__global__ __launch_bounds__(256) void fused_scan_kernel(
    const float* __restrict__ x, const float* __restrict__ decay,
    const float* __restrict__ freq, float* __restrict__ y,
    float2* __restrict__ Agg, float2* __restrict__ Inc,
    int* __restrict__ flags, int* __restrict__ ticket) {
  __shared__ int s_ord;
  if (threadIdx.x == 0)
    s_ord = __hip_atomic_fetch_add(ticket, 1, __ATOMIC_RELAXED,
                                   __HIP_MEMORY_SCOPE_AGENT);
  __syncthreads();
  const int o = s_ord;      // flat chunk id = 4*c + b (ticket order)
  const int c = o >> 2;     // chunk within batch
  const int b = o & 3;      // batch
  const int d = threadIdx.x * 4;

  // r and r^TB per channel
  float4 dv = *(const float4*)(decay + d);
  float4 fv = *(const float4*)(freq + d);
  float rr[4], ri[4], rLr[4], rLi[4];
  {
    float av[4] = {fabsf(dv.x), fabsf(dv.y), fabsf(dv.z), fabsf(dv.w)};
    float wv[4] = {fv.x, fv.y, fv.z, fv.w};
#pragma unroll
    for (int k = 0; k < 4; ++k) {
      float e = expf(-av[k]);
      rr[k] = e * cosf(wv[k]);
      ri[k] = e * sinf(wv[k]);
      float eL = expf(-av[k] * (float)TB);
      rLr[k] = eL * cosf(wv[k] * (float)TB);
      rLi[k] = eL * sinf(wv[k] * (float)TB);
    }
  }

  // ---- phase 1: local scan, provisional y in registers ----
  const float* xp = x + ((size_t)b * T_DIM + (size_t)c * TB) * D_DIM + d;
  float yv[4][TB];
  float zr[4] = {0.f, 0.f, 0.f, 0.f}, zi[4] = {0.f, 0.f, 0.f, 0.f};
#pragma unroll
  for (int t = 0; t < TB; ++t) {
    floatx4 xv =
        __builtin_nontemporal_load((const floatx4*)(xp + (size_t)t * D_DIM));
#pragma unroll
    for (int k = 0; k < 4; ++k) {
      float nr = fmaf(rr[k], zr[k], fmaf(-ri[k], zi[k], xv[k]));
      float ni = fmaf(rr[k], zi[k], ri[k] * zr[k]);
      zr[k] = nr;
      zi[k] = ni;
      yv[k][t] = nr;
    }
  }

  // ---- publish aggregate (chunk 0 publishes inclusive directly below) ----
  if (c > 0) {
    float2* ap = Agg + (size_t)o * D_DIM + d;
    *(float4*)(ap)     = make_float4(zr[0], zi[0], zr[1], zi[1]);
    *(float4*)(ap + 2) = make_float4(zr[2], zi[2], zr[3], zi[3]);
    __threadfence();
    __syncthreads();
    if (threadIdx.x == 0)
      __hip_atomic_store(&flags[o], 1, __ATOMIC_RELEASE,
                         __HIP_MEMORY_SCOPE_AGENT);
  }

  // ---- phase 2: decoupled look-back -> Zin = (Sr, Si) ----
  float Sr[4] = {0, 0, 0, 0}, Si[4] = {0, 0, 0, 0};
  if (c > 0) {
    float mr[4] = {1, 1, 1, 1}, mi[4] = {0, 0, 0, 0};
    int fj = o - 4;  // predecessor chunk, same batch
    while (true) {
      int s;
      do {
        s = __hip_atomic_load(&flags[fj], __ATOMIC_ACQUIRE,
                              __HIP_MEMORY_SCOPE_AGENT);
        if (s != 0) break;
        __builtin_amdgcn_s_sleep(2);
      } while (true);
      const float2* pp = (s == 2 ? Inc : Agg) + (size_t)fj * D_DIM + d;
      float4 v0 = *(const float4*)(pp);
      float4 v1 = *(const float4*)(pp + 2);
      float pr[4] = {v0.x, v0.z, v1.x, v1.z};
      float pi[4] = {v0.y, v0.w, v1.y, v1.w};
#pragma unroll
      for (int k = 0; k < 4; ++k) {
        Sr[k] = fmaf(mr[k], pr[k], fmaf(-mi[k], pi[k], Sr[k]));
        Si[k] = fmaf(mr[k], pi[k], fmaf(mi[k], pr[k], Si[k]));
      }
      if (s == 2) break;  // consumed an inclusive prefix: done
#pragma unroll
      for (int k = 0; k < 4; ++k) {
        float tmr = fmaf(mr[k], rLr[k], -mi[k] * rLi[k]);
        float tmi = fmaf(mr[k], rLi[k], mi[k] * rLr[k]);
        mr[k] = tmr;
        mi[k] = tmi;
      }
      fj -= 4;
    }
  }

  // ---- publish inclusive: Inc = z_end_local + r^TB * Zin ----
  if (c < CB - 1) {
    float ir[4], ii[4];
#pragma unroll
    for (int k = 0; k < 4; ++k) {
      ir[k] = fmaf(rLr[k], Sr[k], fmaf(-rLi[k], Si[k], zr[k]));
      ii[k] = fmaf(rLr[k], Si[k], fmaf(rLi[k], Sr[k], zi[k]));
    }
    float2* ip = Inc + (size_t)o * D_DIM + d;
    *(float4*)(ip)     = make_float4(ir[0], ii[0], ir[1], ii[1]);
    *(float4*)(ip + 2) = make_float4(ir[2], ii[2], ir[3], ii[3]);
    __threadfence();
    __syncthreads();
    if (threadIdx.x == 0)
      __hip_atomic_store(&flags[o], 2, __ATOMIC_RELEASE,
                         __HIP_MEMORY_SCOPE_AGENT);
  }

  // ---- phase 3: y[t] = yv[t] + Re(q),  q = r^{t+1} * Zin ----
  float qr[4], qi[4];
#pragma unroll
  for (int k = 0; k < 4; ++k) {
    qr[k] = fmaf(rr[k], Sr[k], -ri[k] * Si[k]);
    qi[k] = fmaf(rr[k], Si[k], ri[k] * Sr[k]);
  }
  float* yp = y + ((size_t)b * T_DIM + (size_t)c * TB) * D_DIM + d;
#pragma unroll
  for (int t = 0; t < TB; ++t) {
    floatx4 out = {yv[0][t] + qr[0], yv[1][t] + qr[1], yv[2][t] + qr[2],
                   yv[3][t] + qr[3]};
    __builtin_nontemporal_store(out, (floatx4*)(yp + (size_t)t * D_DIM));
#pragma unroll
    for (int k = 0; k < 4; ++k) {
      float nqr = fmaf(rr[k], qr[k], -ri[k] * qi[k]);
      float nqi = fmaf(rr[k], qi[k], ri[k] * qr[k]);
      qr[k] = nqr;
      qi[k] = nqi;
    }
  }
}

extern "C" void kernel_launch(void* const* d_in, const int* in_sizes, int n_in,
                              void* d_out, int out_size, void* d_ws, size_t ws_size,
                              hipStream_t stream) {
  const float* x     = (const float*)d_in[0];
  const float* decay = (const float*)d_in[1];
  const float* freq  = (const float*)d_in[2];
  float* y = (float*)d_out;

  char* ws = (char*)d_ws;
  int* flags  = (int*)ws;           // NCHUNK flags + 1 ticket (zeroed below)
  int* ticket = flags + NCHUNK;
  float2* Agg = (float2*)(ws + 8192);            // 8 MiB
  float2* Inc = Agg + (size_t)NCHUNK * D_DIM;    // 8 MiB

  hipMemsetAsync(ws, 0, (NCHUNK + 1) * sizeof(int), stream);
  fused_scan_kernel<<<NCHUNK, 256, 0, stream>>>(x, decay, freq, y, Agg, Inc,
                                                flags, ticket);
}